// Round 5
// baseline (448.865 us; speedup 1.0000x reference)
//
#include <hip/hip_runtime.h>
#include <hip/hip_bf16.h>
#include <stdint.h>

typedef __bf16 bf16_t;
typedef bf16_t bf16x8 __attribute__((ext_vector_type(8)));
typedef bf16_t bf16x2 __attribute__((ext_vector_type(2)));
typedef float f32x4 __attribute__((ext_vector_type(4)));

#define E_N 65536
#define T_N 262144

__device__ __forceinline__ float silu_f(float v) {
  return v / (1.0f + __expf(-v));
}

// B-row permutation: B row (tj*16+l16) holds real output column
// 32*(tj>>1) + 2*l16 + (tj&1) -> lane's acc pair = 2 consecutive real cols.
__device__ __forceinline__ int permrow(int n) {
  return (n & ~31) | ((n & 1) << 4) | ((n & 30) >> 1);
}

__device__ __forceinline__ uint32_t pack_bf16(float a, float b) {
  union { bf16x2 h; uint32_t u; } u;
  u.h[0] = (bf16_t)a; u.h[1] = (bf16_t)b;
  return u.u;
}

__device__ __forceinline__ float2 ubf2f(uint32_t v) {
  union { uint32_t u; bf16x2 h; } c; c.u = v;
  return make_float2((float)c.h[0], (float)c.h[1]);
}

// packed bf16x2 global atomic add (overflow path only)
__device__ __forceinline__ void atomic_pk_add_bf16(bf16_t* addr, uint32_t val) {
  asm volatile("global_atomic_pk_add_bf16 %0, %1, off" :: "v"(addr), "v"(val) : "memory");
}

__device__ __forceinline__ bf16x8 pack8(float4 a, float4 b) {
  union { bf16x8 v; uint32_t u[4]; } z;
  z.u[0] = pack_bf16(a.x, a.y); z.u[1] = pack_bf16(a.z, a.w);
  z.u[2] = pack_bf16(b.x, b.y); z.u[3] = pack_bf16(b.z, b.w);
  return z.v;
}

// ---- MFMA tile GEMM: A from swizzled stride-128 LDS, B direct from global ----
// A elem (row,k) at row*128 + (((k>>3) ^ (row&15))<<3) + (k&7).
template<int KI, int NTJ, int BS>
__device__ __forceinline__ void gemm_bg(const bf16_t* A, const bf16_t* __restrict__ Bg,
                                        int mb, int nb, int l16, int q,
                                        f32x4 (&acc)[2][NTJ]) {
  bf16x8 bfr[KI][NTJ];
  const bf16_t* bp = Bg + (nb + l16) * BS + q * 8;
#pragma unroll
  for (int kt = 0; kt < KI; ++kt)
#pragma unroll
    for (int tj = 0; tj < NTJ; ++tj)
      bfr[kt][tj] = *(const bf16x8*)(bp + tj * 16 * BS + kt * 32);
#pragma unroll
  for (int kt = 0; kt < KI; ++kt) {
    const int sw = ((kt * 4 + q) ^ l16) << 3;
    bf16x8 a0 = *(const bf16x8*)(A + ((mb + l16) << 7) + sw);
    bf16x8 a1 = *(const bf16x8*)(A + ((mb + 16 + l16) << 7) + sw);
#pragma unroll
    for (int tj = 0; tj < NTJ; ++tj) {
      acc[0][tj] = __builtin_amdgcn_mfma_f32_16x16x32_bf16(a0, bfr[kt][tj], acc[0][tj], 0, 0, 0);
      acc[1][tj] = __builtin_amdgcn_mfma_f32_16x16x32_bf16(a1, bfr[kt][tj], acc[1][tj], 0, 0, 0);
    }
  }
}

// ---- MFMA tile GEMM: A in registers, B from global, double-buffered B ----
template<int KI, int NTJ, int BS>
__device__ __forceinline__ void gemm_rg(const bf16x8 (&a0)[KI], const bf16x8 (&a1)[KI],
                                        const bf16_t* __restrict__ Bg,
                                        int nb, int l16, int q, f32x4 (&acc)[2][NTJ]) {
  const bf16_t* bp = Bg + (nb + l16) * BS + q * 8;
  bf16x8 bcur[NTJ], bnxt[NTJ];
#pragma unroll
  for (int tj = 0; tj < NTJ; ++tj) bcur[tj] = *(const bf16x8*)(bp + tj * 16 * BS);
#pragma unroll
  for (int kt = 0; kt < KI; ++kt) {
    if (kt + 1 < KI) {
#pragma unroll
      for (int tj = 0; tj < NTJ; ++tj)
        bnxt[tj] = *(const bf16x8*)(bp + tj * 16 * BS + (kt + 1) * 32);
    }
#pragma unroll
    for (int tj = 0; tj < NTJ; ++tj) {
      acc[0][tj] = __builtin_amdgcn_mfma_f32_16x16x32_bf16(a0[kt], bcur[tj], acc[0][tj], 0, 0, 0);
      acc[1][tj] = __builtin_amdgcn_mfma_f32_16x16x32_bf16(a1[kt], bcur[tj], acc[1][tj], 0, 0, 0);
    }
#pragma unroll
    for (int tj = 0; tj < NTJ; ++tj) bcur[tj] = bnxt[tj];
  }
}

// =====================  K0: weight preprocessing  =====================
__global__ void prep_kernel(
    const float* __restrict__ W_ji, const float* __restrict__ W_kj,
    const float* __restrict__ W_down, const float* __restrict__ W_up,
    const float* __restrict__ rb1, const float* __restrict__ rb2,
    const float* __restrict__ W_lin, const float* __restrict__ ra1,
    const float* __restrict__ ra2, const float* __restrict__ W_rbf1,
    const float* __restrict__ W_rbf2, const float* __restrict__ W_sbf1,
    const float* __restrict__ W_sbf2,
    bf16_t* __restrict__ wjiT, bf16_t* __restrict__ wkjT,
    bf16_t* __restrict__ wdownT, bf16_t* __restrict__ wupT,
    bf16_t* __restrict__ rb1T, bf16_t* __restrict__ rb2T,
    bf16_t* __restrict__ linT, bf16_t* __restrict__ ra1T,
    bf16_t* __restrict__ ra2T, bf16_t* __restrict__ wcb,
    bf16_t* __restrict__ wsT)
{
  const int tid = threadIdx.x;
  const int bx = blockIdx.x;
  if (bx < 112) {
    const int c = bx * 256 + tid;
    const float* src; bf16_t* dst; int n, k8, N, K;
    if (c < 22528) {
      const int m = c >> 11, w = c & 2047;
      n = w >> 4; k8 = w & 15; N = 128; K = 128;
      if (m == 0)      { src = W_ji;  dst = wjiT; }
      else if (m <= 5) { src = W_kj + m * 16384; dst = wkjT + (m - 1) * 16384; }
      else if (m == 6) { src = rb1;   dst = rb1T; }
      else if (m == 7) { src = rb2;   dst = rb2T; }
      else if (m == 8) { src = W_lin; dst = linT; }
      else if (m == 9) { src = ra1;   dst = ra1T; }
      else             { src = ra2;   dst = ra2T; }
    } else if (c < 27648) {
      const int m = (c - 22528) >> 10, w = (c - 22528) & 1023;
      n = w >> 4; k8 = w & 15; N = 64; K = 128;
      src = W_down + (m + 1) * 8192; dst = wdownT + m * 8192;
    } else {
      const int w = c - 27648;
      n = w >> 3; k8 = w & 7; N = 128; K = 64;
      src = W_up; dst = wupT;
    }
    bf16_t t[8];
#pragma unroll
    for (int j = 0; j < 8; ++j) t[j] = (bf16_t)src[(k8 * 8 + j) * N + n];
    *(uint4*)(dst + permrow(n) * K + k8 * 8) = *(const uint4*)t;
  } else if (bx < 115) {
    const int o = (bx - 112) * 256 + tid;
    if (o < 640) {
      const int slot = o >> 7, n = o & 127;
      const int b = slot + 1;
      bf16_t t[32];
#pragma unroll
      for (int k = 0; k < 32; ++k) t[k] = (bf16_t)0.f;
#pragma unroll
      for (int r = 0; r < 6; ++r) {
        float s = 0.f;
#pragma unroll
        for (int c = 0; c < 8; ++c)
          s += W_rbf1[b * 48 + r * 8 + c] * W_rbf2[b * 1024 + c * 128 + n];
        t[r] = (bf16_t)s;
      }
      bf16_t* dst = wcb + slot * 4096 + permrow(n) * 32;
#pragma unroll
      for (int g = 0; g < 4; ++g) *(uint4*)(dst + g * 8) = *(const uint4*)(t + g * 8);
    }
  } else {
    const int o = (bx - 115) * 256 + tid;
    if (o < 320) {
      const int slot = o >> 6, j = o & 63;
      const int b = slot + 1;
      bf16_t t[64];
#pragma unroll
      for (int s = 0; s < 64; ++s) {
        float v = 0.f;
        if (s < 42) {
#pragma unroll
          for (int c = 0; c < 8; ++c)
            v += W_sbf1[b * 336 + s * 8 + c] * W_sbf2[b * 512 + c * 64 + j];
        }
        t[s] = (bf16_t)v;
      }
      bf16_t* dst = wsT + (slot * 64 + permrow(j)) * 64;
#pragma unroll
      for (int g = 0; g < 8; ++g) *(uint4*)(dst + g * 8) = *(const uint4*)(t + g * 8);
    }
  }
}

// =====================  K_fill: bucket-CSR build  =====================
__global__ void fill_kernel(const int* __restrict__ idx_ji, int* __restrict__ cnt,
                            int* __restrict__ bucket, int* __restrict__ ovfc,
                            int* __restrict__ ovf)
{
  const int t = blockIdx.x * 256 + threadIdx.x;
  const int ji = idx_ji[t];
  const int pos = atomicAdd(&cnt[ji], 1);
  if (pos < 12) bucket[ji * 12 + pos] = t;
  else {
    const int o = atomicAdd(ovfc, 1);
    if (o < 65536) ovf[o] = t;
  }
}

// =====================  K1: edge-level GEMMs (branch-parallel, no A-LDS)  =====================
__global__ __launch_bounds__(256, 4)
void edge_kernel(const float* __restrict__ x, const float* __restrict__ rbf,
                 const float* __restrict__ b_kj, const float* __restrict__ b_ji,
                 const bf16_t* __restrict__ wjiT, const bf16_t* __restrict__ wkjT,
                 const bf16_t* __restrict__ wdownT, const bf16_t* __restrict__ wcb,
                 bf16_t* __restrict__ x_ji_out, bf16_t* __restrict__ down)
{
  __shared__ bf16_t tmpA[64 * 128];
  __shared__ bf16_t rbfA[64 * 32];     // K=32 zero-padded, swizzled (k8^row&3)
  __shared__ float biasS[128];

  const int tid = threadIdx.x;
  const int lane = tid & 63, wv = tid >> 6;
  const int q = lane >> 4, l16 = lane & 15;
  const int mb = (wv >> 1) * 32, nb = (wv & 1) * 64;
  const int R = blockIdx.x * 64;
  const int br = blockIdx.y;   // 0 = x_ji, 1..5 = branch pipelines

  if (tid < 128) biasS[tid] = (br == 0) ? b_ji[tid] : b_kj[br * 128 + tid];
  if (br != 0 && tid < 64) {
    const float* rg = rbf + (size_t)(R + tid) * 6;
    bf16_t t[8] = {(bf16_t)rg[0], (bf16_t)rg[1], (bf16_t)rg[2],
                   (bf16_t)rg[3], (bf16_t)rg[4], (bf16_t)rg[5],
                   (bf16_t)0.f, (bf16_t)0.f};
    const uint4 z = {0, 0, 0, 0};
    bf16_t* dst = rbfA + tid * 32;
#pragma unroll
    for (int g = 0; g < 4; ++g) *(uint4*)(dst + g * 8) = z;
    *(uint4*)(dst + ((tid & 3) << 3)) = *(const uint4*)t;
  }

  // A-fragments of x straight from global (fp32 -> bf16 in registers)
  bf16x8 af0[4], af1[4];
  {
    const float* xr = x + (size_t)(R + mb + l16) * 128 + q * 8;
#pragma unroll
    for (int kt = 0; kt < 4; ++kt) {
      float4 v0 = *(const float4*)(xr + kt * 32);
      float4 v1 = *(const float4*)(xr + kt * 32 + 4);
      float4 w0 = *(const float4*)(xr + 16 * 128 + kt * 32);
      float4 w1 = *(const float4*)(xr + 16 * 128 + kt * 32 + 4);
      af0[kt] = pack8(v0, v1);
      af1[kt] = pack8(w0, w1);
    }
  }
  __syncthreads();

  const bf16_t* WB = (br == 0) ? wjiT : wkjT + (size_t)(br - 1) * 16384;
  f32x4 acc[2][4] = {};
  gemm_rg<4, 4, 128>(af0, af1, WB, nb, l16, q, acc);

  if (br == 0) {
#pragma unroll
    for (int ti = 0; ti < 2; ++ti)
#pragma unroll
      for (int r = 0; r < 4; ++r) {
        const int row = mb + ti * 16 + q * 4 + r;
#pragma unroll
        for (int gl = 0; gl < 2; ++gl) {
          const int col0 = nb + gl * 32 + 2 * l16;
          const float2 b2 = *(const float2*)&biasS[col0];
          *(uint32_t*)&x_ji_out[(size_t)(R + row) * 128 + col0] =
              pack_bf16(silu_f(acc[ti][2 * gl][r] + b2.x),
                        silu_f(acc[ti][2 * gl + 1][r] + b2.y));
        }
      }
    return;
  }

  // rbf_p = rbf @ Wc (K=6 padded to 32), B-frags direct from wcb
  f32x4 accr[2][4] = {};
  {
    const int sw = (q ^ (l16 & 3)) << 3;
    bf16x8 a0 = *(const bf16x8*)(rbfA + ((mb + l16) << 5) + sw);
    bf16x8 a1 = *(const bf16x8*)(rbfA + ((mb + 16 + l16) << 5) + sw);
    const bf16_t* wb = wcb + (size_t)(br - 1) * 4096 + (nb + l16) * 32 + q * 8;
#pragma unroll
    for (int tj = 0; tj < 4; ++tj) {
      bf16x8 b = *(const bf16x8*)(wb + tj * 16 * 32);
      accr[0][tj] = __builtin_amdgcn_mfma_f32_16x16x32_bf16(a0, b, accr[0][tj], 0, 0, 0);
      accr[1][tj] = __builtin_amdgcn_mfma_f32_16x16x32_bf16(a1, b, accr[1][tj], 0, 0, 0);
    }
  }

  // tmp = silu(x@Wkj + b) * rbf_p  -> swizzled A-layout in tmpA
#pragma unroll
  for (int ti = 0; ti < 2; ++ti)
#pragma unroll
    for (int r = 0; r < 4; ++r) {
      const int row = mb + ti * 16 + q * 4 + r;
#pragma unroll
      for (int gl = 0; gl < 2; ++gl) {
        const int col0 = nb + gl * 32 + 2 * l16;
        const float2 b2 = *(const float2*)&biasS[col0];
        const float v0 = silu_f(acc[ti][2 * gl][r] + b2.x) * accr[ti][2 * gl][r];
        const float v1 = silu_f(acc[ti][2 * gl + 1][r] + b2.y) * accr[ti][2 * gl + 1][r];
        *(uint32_t*)&tmpA[(row << 7) + ((((col0 >> 3) ^ (row & 15)) << 3) | (col0 & 7))] =
            pack_bf16(v0, v1);
      }
    }
  __syncthreads();

  const int nb2 = (wv & 1) * 32;
  f32x4 acc2[2][2] = {};
  gemm_bg<4, 2, 128>(tmpA, wdownT + (size_t)(br - 1) * 8192, mb, nb2, l16, q, acc2);
  // down layout: [E][5][64]
#pragma unroll
  for (int ti = 0; ti < 2; ++ti)
#pragma unroll
    for (int r = 0; r < 4; ++r) {
      const int row = mb + ti * 16 + q * 4 + r;
      const int col0 = nb2 + 2 * l16;
      *(uint32_t*)&down[((size_t)(R + row) * 5 + (br - 1)) * 64 + col0] =
          pack_bf16(silu_f(acc2[ti][0][r]), silu_f(acc2[ti][1][r]));
    }
}

// =====================  K3: triplet — MFMA + select; writes contrib[t][64]  =====================
__global__ __launch_bounds__(256, 3)
void triplet_kernel(const float* __restrict__ sbf, const int* __restrict__ idx_kj,
                    const int* __restrict__ bt,
                    const float* __restrict__ alpha_p, const bf16_t* __restrict__ wsT,
                    const bf16_t* __restrict__ down, bf16_t* __restrict__ contrib)
{
  __shared__ bf16_t s_sbf[64 * 64];    // K=42 padded to 64, swizzle (k8^row&7)
  __shared__ bf16_t spC[64 * 344];     // [t][320 cols], pad for banks
  __shared__ int s_kj[64], s_bs[64];

  const int tid = threadIdx.x;
  const int lane = tid & 63, wv = tid >> 6;
  const int q = lane >> 4, l16 = lane & 15;
  const int base = blockIdx.x * 64;

  if (tid < 64) {
    const int kj = idx_kj[base + tid];
    s_kj[tid] = kj;
    s_bs[tid] = bt[kj];   // 0..4 = slot of masked branch (branch = bt+1)
  }
#pragma unroll
  for (int it = 0; it < 2; ++it) {
    const int i = tid + it * 256;
    const int row = i >> 3, k8 = i & 7;
    const float* sg = sbf + (size_t)(base + row) * 42 + k8 * 8;
    bf16_t t[8];
#pragma unroll
    for (int jj = 0; jj < 8; ++jj)
      t[jj] = (k8 * 8 + jj < 42) ? (bf16_t)sg[jj] : (bf16_t)0.f;
    *(uint4*)(s_sbf + (row << 6) + ((k8 ^ (row & 7)) << 3)) = *(const uint4*)t;
  }
  __syncthreads();

  // GEMM: [64 x 48] @ [48 x 320] ; waves split M x 2, N x 2 (10 tiles each)
  const int mb = (wv & 1) * 32;
  const int tb0 = (wv >> 1) * 10;
  f32x4 acc[2][10] = {};
#pragma unroll
  for (int kt = 0; kt < 2; ++kt) {
    const int sw = (((kt << 2) + q) ^ (l16 & 7)) << 3;
    bf16x8 a0 = *(const bf16x8*)(s_sbf + ((mb + l16) << 6) + sw);
    bf16x8 a1 = *(const bf16x8*)(s_sbf + ((mb + 16 + l16) << 6) + sw);
    const bf16_t* bp = wsT + (tb0 * 16 + l16) * 64 + (kt << 5) + (q << 3);
#pragma unroll
    for (int tj = 0; tj < 10; ++tj) {
      bf16x8 b = *(const bf16x8*)(bp + tj * 1024);
      acc[0][tj] = __builtin_amdgcn_mfma_f32_16x16x32_bf16(a0, b, acc[0][tj], 0, 0, 0);
      acc[1][tj] = __builtin_amdgcn_mfma_f32_16x16x32_bf16(a1, b, acc[1][tj], 0, 0, 0);
    }
  }
#pragma unroll
  for (int ti = 0; ti < 2; ++ti)
#pragma unroll
    for (int r = 0; r < 4; ++r) {
      const int row = mb + ti * 16 + q * 4 + r;
#pragma unroll
      for (int tp = 0; tp < 5; ++tp) {
        const int t0 = tb0 + 2 * tp;
        const int col = (t0 >> 2) * 64 + (((t0 & 3) >> 1) << 5) + 2 * l16;
        *(uint32_t*)&spC[row * 344 + col] =
            pack_bf16(acc[ti][2 * tp][r], acc[ti][2 * tp + 1][r]);
      }
    }
  __syncthreads();

  // Phase 2: two triplets per wave-iteration; bf16x2 gathers + contiguous store.
  const float alpha = alpha_p[0];
  const float oma = 1.f - alpha;
  const int hf = lane >> 5;          // which triplet of the pair
  const int j0 = (lane & 31) * 2;    // 2 consecutive j per lane

  uint32_t G5[8], GB[8];
#pragma unroll
  for (int ii = 0; ii < 8; ++ii) {
    const int t = wv * 16 + ii * 2 + hf;
    const bf16_t* dr = down + (size_t)s_kj[t] * 320;
    G5[ii] = *(const uint32_t*)(dr + 256 + j0);
    GB[ii] = *(const uint32_t*)(dr + s_bs[t] * 64 + j0);
  }
#pragma unroll
  for (int ii = 0; ii < 8; ++ii) {
    const int t = wv * 16 + ii * 2 + hf;
    const int slot = s_bs[t];
    const float2 d5 = ubf2f(*(const uint32_t*)&spC[t * 344 + 256 + j0]);
    const float2 db = ubf2f(*(const uint32_t*)&spC[t * 344 + slot * 64 + j0]);
    const float2 g5 = ubf2f(G5[ii]);
    const float2 gb = ubf2f(GB[ii]);
    const float r0 = alpha * g5.x * d5.x + oma * gb.x * db.x;
    const float r1 = alpha * g5.y * d5.y + oma * gb.y * db.y;
    *(uint32_t*)&contrib[(size_t)(base + t) * 64 + j0] = pack_bf16(r0, r1);
  }
}

// =====================  K_gather: per-edge segment sum (no atomics)  =====================
__global__ __launch_bounds__(256, 8)
void gather_kernel(const int* __restrict__ cnt, const int* __restrict__ bucket,
                   const bf16_t* __restrict__ contrib, bf16_t* __restrict__ xkj)
{
  const int wv = threadIdx.x >> 6, lane = threadIdx.x & 63;
  const int e = blockIdx.x * 4 + wv;
  int n = cnt[e]; if (n > 12) n = 12;
  const int tk = (lane < 12) ? bucket[e * 12 + lane] : 0;
  float acc = 0.f;
  for (int k = 0; k < n; ++k) {
    const int t = __shfl(tk, k);
    acc += (float)contrib[(size_t)t * 64 + lane];
  }
  xkj[(size_t)e * 64 + lane] = (bf16_t)acc;
}

// =====================  K_ovf: rare degree>12 entries via pk atomics  =====================
__global__ void ovf_kernel(const int* __restrict__ ovfc, const int* __restrict__ ovf,
                           const int* __restrict__ idx_ji,
                           const bf16_t* __restrict__ contrib, bf16_t* __restrict__ xkj)
{
  int m = *ovfc; if (m > 65536) m = 65536;
  const int gid = blockIdx.x * 256 + threadIdx.x;
  const int entry0 = gid >> 5, pl = gid & 31;
  for (int i = entry0; i < m; i += (gridDim.x * 256) >> 5) {
    const int t = ovf[i];
    const int ji = idx_ji[t];
    const uint32_t v = *(const uint32_t*)&contrib[(size_t)t * 64 + pl * 2];
    atomic_pk_add_bf16(&xkj[(size_t)ji * 64 + pl * 2], v);
  }
}

// =====================  K4: fused epilogue chain (512 threads, 8 waves)  =====================
__global__ __launch_bounds__(512, 4)
void epi_kernel(const float* __restrict__ x, const bf16_t* __restrict__ x_ji,
                const bf16_t* __restrict__ xkj,
                const bf16_t* __restrict__ wupT,
                const bf16_t* __restrict__ rb1T, const float* __restrict__ rb1_b,
                const bf16_t* __restrict__ rb2T, const float* __restrict__ rb2_b,
                const bf16_t* __restrict__ linT, const float* __restrict__ lin_b,
                const bf16_t* __restrict__ ra1T, const float* __restrict__ ra1_b,
                const bf16_t* __restrict__ ra2T, const float* __restrict__ ra2_b,
                float* __restrict__ out)
{
  __shared__ bf16_t bufA[64 * 128];
  __shared__ bf16_t bufB[64 * 128];
  __shared__ float biasAll[5 * 128];

  const int tid = threadIdx.x;
  const int lane = tid & 63, wv = tid >> 6;
  const int q = lane >> 4, l16 = lane & 15;
  const int mb = (wv >> 2) * 32, nb = (wv & 3) * 32;
  const int R = blockIdx.x * 64;

  { // stage xkj tile (bf16 [64][64]) -> swizzled LDS
    const int row = tid >> 3, k8 = tid & 7;
    *(uint4*)(bufA + (row << 7) + ((k8 ^ (row & 15)) << 3)) =
        ((const uint4*)(xkj + (size_t)R * 64))[tid];
  }
  if (tid < 128) {
    biasAll[tid]       = rb1_b[tid];
    biasAll[128 + tid] = rb2_b[tid];
    biasAll[256 + tid] = lin_b[tid];
    biasAll[384 + tid] = ra1_b[tid];
    biasAll[512 + tid] = ra2_b[tid];
  }
  __syncthreads();

  f32x4 hreg[2][2];
  { // h = x_ji + silu(xkj @ W_up)  -> bufB
    f32x4 acc[2][2] = {};
    gemm_bg<2, 2, 64>(bufA, wupT, mb, nb, l16, q, acc);
#pragma unroll
    for (int ti = 0; ti < 2; ++ti)
#pragma unroll
      for (int r = 0; r < 4; ++r) {
        const int row = mb + ti * 16 + q * 4 + r;
        const int col0 = nb + 2 * l16;
        union { uint32_t u; bf16x2 h; } xj;
        xj.u = *(const uint32_t*)&x_ji[(size_t)(R + row) * 128 + col0];
        const float h0 = (float)xj.h[0] + silu_f(acc[ti][0][r]);
        const float h1 = (float)xj.h[1] + silu_f(acc[ti][1][r]);
        hreg[ti][0][r] = h0;
        hreg[ti][1][r] = h1;
        *(uint32_t*)&bufB[(row << 7) + ((((col0 >> 3) ^ (row & 15)) << 3) | (col0 & 7))] =
            pack_bf16(h0, h1);
      }
  }

#define EPI_STAGE(ASRC, WPTR, BROW, BODY)                                        \
  __syncthreads();                                                               \
  {                                                                              \
    f32x4 acc[2][2] = {};                                                        \
    gemm_bg<4, 2, 128>(ASRC, WPTR, mb, nb, l16, q, acc);                         \
    _Pragma("unroll")                                                            \
    for (int ti = 0; ti < 2; ++ti)                                               \
      _Pragma("unroll")                                                          \
      for (int r = 0; r < 4; ++r) {                                              \
        const int row = mb + ti * 16 + q * 4 + r;                                \
        const int col0 = nb + 2 * l16;                                           \
        const float2 b2 = *(const float2*)&biasAll[BROW * 128 + col0];           \
        const float g0 = acc[ti][0][r] + b2.x;                                   \
        const float g1 = acc[ti][1][r] + b2.y;                                   \
        BODY                                                                     \
      }                                                                          \
  }

  // u = silu(h @ rb1 + b) -> bufA
  EPI_STAGE(bufB, rb1T, 0, {
    *(uint32_t*)&bufA[(row << 7) + ((((col0 >> 3) ^ (row & 15)) << 3) | (col0 & 7))] =
        pack_bf16(silu_f(g0), silu_f(g1));
  })

  // h += silu(u @ rb2 + b) -> bufB
  EPI_STAGE(bufA, rb2T, 1, {
    const float h0 = hreg[ti][0][r] + silu_f(g0);
    const float h1 = hreg[ti][1][r] + silu_f(g1);
    hreg[ti][0][r] = h0; hreg[ti][1][r] = h1;
    *(uint32_t*)&bufB[(row << 7) + ((((col0 >> 3) ^ (row & 15)) << 3) | (col0 & 7))] =
        pack_bf16(h0, h1);
  })

  // h = silu(h @ W_lin + b) + x -> bufA
  EPI_STAGE(bufB, linT, 2, {
    const float2 xv = *(const float2*)&x[(size_t)(R + row) * 128 + col0];
    const float h0 = silu_f(g0) + xv.x;
    const float h1 = silu_f(g1) + xv.y;
    hreg[ti][0][r] = h0; hreg[ti][1][r] = h1;
    *(uint32_t*)&bufA[(row << 7) + ((((col0 >> 3) ^ (row & 15)) << 3) | (col0 & 7))] =
        pack_bf16(h0, h1);
  })

  // u = silu(h @ ra1 + b) -> bufB
  EPI_STAGE(bufA, ra1T, 3, {
    *(uint32_t*)&bufB[(row << 7) + ((((col0 >> 3) ^ (row & 15)) << 3) | (col0 & 7))] =
        pack_bf16(silu_f(g0), silu_f(g1));
  })

  // out = h + silu(u @ ra2 + b)
  EPI_STAGE(bufB, ra2T, 4, {
    float2 o;
    o.x = hreg[ti][0][r] + silu_f(g0);
    o.y = hreg[ti][1][r] + silu_f(g1);
    *(float2*)&out[(size_t)(R + row) * 128 + col0] = o;
  })
#undef EPI_STAGE
}

extern "C" void kernel_launch(void* const* d_in, const int* in_sizes, int n_in,
                              void* d_out, int out_size, void* d_ws, size_t ws_size,
                              hipStream_t stream)
{
  (void)in_sizes; (void)n_in; (void)out_size; (void)ws_size;
  const float* x      = (const float*)d_in[0];
  const float* rbf    = (const float*)d_in[1];
  const float* sbf    = (const float*)d_in[2];
  const int*   idx_kj = (const int*)d_in[3];
  const int*   idx_ji = (const int*)d_in[4];
  const int*   bt     = (const int*)d_in[5];
  const float* alpha  = (const float*)d_in[7];
  const float* W_kj   = (const float*)d_in[8];
  const float* b_kj   = (const float*)d_in[9];
  const float* W_rbf1 = (const float*)d_in[10];
  const float* W_rbf2 = (const float*)d_in[11];
  const float* W_sbf1 = (const float*)d_in[12];
  const float* W_sbf2 = (const float*)d_in[13];
  const float* W_down = (const float*)d_in[14];
  const float* W_ji   = (const float*)d_in[15];
  const float* b_ji   = (const float*)d_in[16];
  const float* W_up   = (const float*)d_in[17];
  const float* rb1_w  = (const float*)d_in[18];
  const float* rb1_b  = (const float*)d_in[19];
  const float* rb2_w  = (const float*)d_in[20];
  const float* rb2_b  = (const float*)d_in[21];
  const float* W_lin  = (const float*)d_in[22];
  const float* b_lin  = (const float*)d_in[23];
  const float* ra1_w  = (const float*)d_in[24];
  const float* ra1_b  = (const float*)d_in[25];
  const float* ra2_w  = (const float*)d_in[26];
  const float* ra2_b  = (const float*)d_in[27];

  char* ws = (char*)d_ws;
  bf16_t* down    = (bf16_t*)(ws);                 // [E][5][64] bf16 = 41,943,040
  bf16_t* x_ji    = (bf16_t*)(ws + 41943040);      // E*128*2   = 16,777,216
  bf16_t* xkj     = (bf16_t*)(ws + 58720256);      // E*64*2    = 8,388,608
  bf16_t* contrib = (bf16_t*)(ws + 67108864);      // T*64*2    = 33,554,432
  char* wbase     = ws + 100663296;
  bf16_t* wjiT   = (bf16_t*)(wbase + 0);
  bf16_t* wkjT   = (bf16_t*)(wbase + 32768);
  bf16_t* wdownT = (bf16_t*)(wbase + 196608);
  bf16_t* wupT   = (bf16_t*)(wbase + 278528);
  bf16_t* rb1T   = (bf16_t*)(wbase + 294912);
  bf16_t* rb2T   = (bf16_t*)(wbase + 327680);
  bf16_t* linT   = (bf16_t*)(wbase + 360448);
  bf16_t* ra1T   = (bf16_t*)(wbase + 393216);
  bf16_t* ra2T   = (bf16_t*)(wbase + 425984);
  bf16_t* wcb    = (bf16_t*)(wbase + 458752);      // 40,960
  bf16_t* wsT    = (bf16_t*)(wbase + 499712);      // 40,960
  int* cnt    = (int*)(wbase + 540672);            // 65536*4 = 262,144
  int* ovfc   = (int*)(wbase + 802816);            // 4 (padded 256)
  int* bucket = (int*)(wbase + 803072);            // 65536*12*4 = 3,145,728
  int* ovf    = (int*)(wbase + 3948800);           // 65536*4 = 262,144

  hipMemsetAsync(cnt, 0, 262400, stream);          // cnt + ovfc
  prep_kernel<<<117, 256, 0, stream>>>(W_ji, W_kj, W_down, W_up, rb1_w, rb2_w,
                                       W_lin, ra1_w, ra2_w, W_rbf1, W_rbf2,
                                       W_sbf1, W_sbf2,
                                       wjiT, wkjT, wdownT, wupT, rb1T, rb2T,
                                       linT, ra1T, ra2T, wcb, wsT);
  fill_kernel<<<T_N / 256, 256, 0, stream>>>(idx_ji, cnt, bucket, ovfc, ovf);
  edge_kernel<<<dim3(E_N / 64, 6), 256, 0, stream>>>(x, rbf, b_kj, b_ji, wjiT,
                                                     wkjT, wdownT, wcb, x_ji, down);
  triplet_kernel<<<T_N / 64, 256, 0, stream>>>(sbf, idx_kj, bt, alpha,
                                               wsT, down, contrib);
  gather_kernel<<<E_N / 4, 256, 0, stream>>>(cnt, bucket, contrib, xkj);
  ovf_kernel<<<32, 256, 0, stream>>>(ovfc, ovf, idx_ji, contrib, xkj);
  epi_kernel<<<E_N / 64, 512, 0, stream>>>(x, x_ji, xkj, wupT, rb1T, rb1_b,
                                           rb2T, rb2_b, linT, b_lin,
                                           ra1T, ra1_b, ra2T, ra2_b,
                                           (float*)d_out);
}

// Round 6
// 436.311 us; speedup vs baseline: 1.0288x; 1.0288x over previous
//
#include <hip/hip_runtime.h>
#include <hip/hip_bf16.h>
#include <stdint.h>

typedef __bf16 bf16_t;
typedef bf16_t bf16x8 __attribute__((ext_vector_type(8)));
typedef bf16_t bf16x2 __attribute__((ext_vector_type(2)));
typedef float f32x4 __attribute__((ext_vector_type(4)));

#define E_N 65536
#define T_N 262144

__device__ __forceinline__ float silu_f(float v) {
  return v / (1.0f + __expf(-v));
}

// B-row permutation: B row (tj*16+l16) holds real output column
// 32*(tj>>1) + 2*l16 + (tj&1) -> lane's acc pair = 2 consecutive real cols.
__device__ __forceinline__ int permrow(int n) {
  return (n & ~31) | ((n & 1) << 4) | ((n & 30) >> 1);
}

__device__ __forceinline__ uint32_t pack_bf16(float a, float b) {
  union { bf16x2 h; uint32_t u; } u;
  u.h[0] = (bf16_t)a; u.h[1] = (bf16_t)b;
  return u.u;
}

__device__ __forceinline__ float2 ubf2f(uint32_t v) {
  union { uint32_t u; bf16x2 h; } c; c.u = v;
  return make_float2((float)c.h[0], (float)c.h[1]);
}

// packed bf16x2 global atomic add (2 adds per atomic word)
__device__ __forceinline__ void atomic_pk_add_bf16(bf16_t* addr, uint32_t val) {
  asm volatile("global_atomic_pk_add_bf16 %0, %1, off" :: "v"(addr), "v"(val) : "memory");
}

__device__ __forceinline__ bf16x8 pack8(float4 a, float4 b) {
  union { bf16x8 v; uint32_t u[4]; } z;
  z.u[0] = pack_bf16(a.x, a.y); z.u[1] = pack_bf16(a.z, a.w);
  z.u[2] = pack_bf16(b.x, b.y); z.u[3] = pack_bf16(b.z, b.w);
  return z.v;
}

// ---- MFMA tile GEMM: A from swizzled stride-128 LDS, B direct from global ----
// A elem (row,k) at row*128 + (((k>>3) ^ (row&15))<<3) + (k&7).
// B global [row][BS] bf16, rows pre-permuted; all B-frags hoisted first.
template<int KI, int NTJ, int BS>
__device__ __forceinline__ void gemm_bg(const bf16_t* A, const bf16_t* __restrict__ Bg,
                                        int mb, int nb, int l16, int q,
                                        f32x4 (&acc)[2][NTJ]) {
  bf16x8 bfr[KI][NTJ];
  const bf16_t* bp = Bg + (nb + l16) * BS + q * 8;
#pragma unroll
  for (int kt = 0; kt < KI; ++kt)
#pragma unroll
    for (int tj = 0; tj < NTJ; ++tj)
      bfr[kt][tj] = *(const bf16x8*)(bp + tj * 16 * BS + kt * 32);
#pragma unroll
  for (int kt = 0; kt < KI; ++kt) {
    const int sw = ((kt * 4 + q) ^ l16) << 3;
    bf16x8 a0 = *(const bf16x8*)(A + ((mb + l16) << 7) + sw);
    bf16x8 a1 = *(const bf16x8*)(A + ((mb + 16 + l16) << 7) + sw);
#pragma unroll
    for (int tj = 0; tj < NTJ; ++tj) {
      acc[0][tj] = __builtin_amdgcn_mfma_f32_16x16x32_bf16(a0, bfr[kt][tj], acc[0][tj], 0, 0, 0);
      acc[1][tj] = __builtin_amdgcn_mfma_f32_16x16x32_bf16(a1, bfr[kt][tj], acc[1][tj], 0, 0, 0);
    }
  }
}

// ---- MFMA tile GEMM: A in registers (reused across calls), B from global, dbuf ----
template<int KI, int NTJ, int BS>
__device__ __forceinline__ void gemm_rg(const bf16x8 (&a0)[KI], const bf16x8 (&a1)[KI],
                                        const bf16_t* __restrict__ Bg,
                                        int nb, int l16, int q, f32x4 (&acc)[2][NTJ]) {
  const bf16_t* bp = Bg + (nb + l16) * BS + q * 8;
  bf16x8 bcur[NTJ], bnxt[NTJ];
#pragma unroll
  for (int tj = 0; tj < NTJ; ++tj) bcur[tj] = *(const bf16x8*)(bp + tj * 16 * BS);
#pragma unroll
  for (int kt = 0; kt < KI; ++kt) {
    if (kt + 1 < KI) {
#pragma unroll
      for (int tj = 0; tj < NTJ; ++tj)
        bnxt[tj] = *(const bf16x8*)(bp + tj * 16 * BS + (kt + 1) * 32);
    }
#pragma unroll
    for (int tj = 0; tj < NTJ; ++tj) {
      acc[0][tj] = __builtin_amdgcn_mfma_f32_16x16x32_bf16(a0[kt], bcur[tj], acc[0][tj], 0, 0, 0);
      acc[1][tj] = __builtin_amdgcn_mfma_f32_16x16x32_bf16(a1[kt], bcur[tj], acc[1][tj], 0, 0, 0);
    }
#pragma unroll
    for (int tj = 0; tj < NTJ; ++tj) bcur[tj] = bnxt[tj];
  }
}

// =====================  K0: weight preprocessing  =====================
__global__ void prep_kernel(
    const float* __restrict__ W_ji, const float* __restrict__ W_kj,
    const float* __restrict__ W_down, const float* __restrict__ W_up,
    const float* __restrict__ rb1, const float* __restrict__ rb2,
    const float* __restrict__ W_lin, const float* __restrict__ ra1,
    const float* __restrict__ ra2, const float* __restrict__ W_rbf1,
    const float* __restrict__ W_rbf2, const float* __restrict__ W_sbf1,
    const float* __restrict__ W_sbf2,
    bf16_t* __restrict__ wjiT, bf16_t* __restrict__ wkjT,
    bf16_t* __restrict__ wdownT, bf16_t* __restrict__ wupT,
    bf16_t* __restrict__ rb1T, bf16_t* __restrict__ rb2T,
    bf16_t* __restrict__ linT, bf16_t* __restrict__ ra1T,
    bf16_t* __restrict__ ra2T, bf16_t* __restrict__ wcb,
    bf16_t* __restrict__ wsT)
{
  const int tid = threadIdx.x;
  const int bx = blockIdx.x;
  if (bx < 112) {
    const int c = bx * 256 + tid;
    const float* src; bf16_t* dst; int n, k8, N, K;
    if (c < 22528) {
      const int m = c >> 11, w = c & 2047;
      n = w >> 4; k8 = w & 15; N = 128; K = 128;
      if (m == 0)      { src = W_ji;  dst = wjiT; }
      else if (m <= 5) { src = W_kj + m * 16384; dst = wkjT + (m - 1) * 16384; }
      else if (m == 6) { src = rb1;   dst = rb1T; }
      else if (m == 7) { src = rb2;   dst = rb2T; }
      else if (m == 8) { src = W_lin; dst = linT; }
      else if (m == 9) { src = ra1;   dst = ra1T; }
      else             { src = ra2;   dst = ra2T; }
    } else if (c < 27648) {
      const int m = (c - 22528) >> 10, w = (c - 22528) & 1023;
      n = w >> 4; k8 = w & 15; N = 64; K = 128;
      src = W_down + (m + 1) * 8192; dst = wdownT + m * 8192;
    } else {
      const int w = c - 27648;
      n = w >> 3; k8 = w & 7; N = 128; K = 64;
      src = W_up; dst = wupT;
    }
    bf16_t t[8];
#pragma unroll
    for (int j = 0; j < 8; ++j) t[j] = (bf16_t)src[(k8 * 8 + j) * N + n];
    *(uint4*)(dst + permrow(n) * K + k8 * 8) = *(const uint4*)t;
  } else if (bx < 115) {
    const int o = (bx - 112) * 256 + tid;
    if (o < 640) {
      const int slot = o >> 7, n = o & 127;
      const int b = slot + 1;
      bf16_t t[32];
#pragma unroll
      for (int k = 0; k < 32; ++k) t[k] = (bf16_t)0.f;
#pragma unroll
      for (int r = 0; r < 6; ++r) {
        float s = 0.f;
#pragma unroll
        for (int c = 0; c < 8; ++c)
          s += W_rbf1[b * 48 + r * 8 + c] * W_rbf2[b * 1024 + c * 128 + n];
        t[r] = (bf16_t)s;
      }
      bf16_t* dst = wcb + slot * 4096 + permrow(n) * 32;
#pragma unroll
      for (int g = 0; g < 4; ++g) *(uint4*)(dst + g * 8) = *(const uint4*)(t + g * 8);
    }
  } else {
    const int o = (bx - 115) * 256 + tid;
    if (o < 320) {
      const int slot = o >> 6, j = o & 63;
      const int b = slot + 1;
      bf16_t t[64];
#pragma unroll
      for (int s = 0; s < 64; ++s) {
        float v = 0.f;
        if (s < 42) {
#pragma unroll
          for (int c = 0; c < 8; ++c)
            v += W_sbf1[b * 336 + s * 8 + c] * W_sbf2[b * 512 + c * 64 + j];
        }
        t[s] = (bf16_t)v;
      }
      bf16_t* dst = wsT + (slot * 64 + permrow(j)) * 64;
#pragma unroll
      for (int g = 0; g < 8; ++g) *(uint4*)(dst + g * 8) = *(const uint4*)(t + g * 8);
    }
  }
}

// =====================  K_xbf: x fp32 -> bf16 once  =====================
__global__ void xbf_kernel(const float* __restrict__ x, bf16_t* __restrict__ xbf) {
  const int i = blockIdx.x * 256 + threadIdx.x;
  float4 a = ((const float4*)x)[2 * i];
  float4 b = ((const float4*)x)[2 * i + 1];
  ((bf16x8*)xbf)[i] = pack8(a, b);
}

// =====================  K1: edge — all 6 branches per block, A in regs  =====================
__global__ __launch_bounds__(256, 3)
void edge_kernel(const bf16_t* __restrict__ xbf, const float* __restrict__ rbf,
                 const float* __restrict__ b_kj, const float* __restrict__ b_ji,
                 const bf16_t* __restrict__ wjiT, const bf16_t* __restrict__ wkjT,
                 const bf16_t* __restrict__ wdownT, const bf16_t* __restrict__ wcb,
                 bf16_t* __restrict__ x_ji_out, bf16_t* __restrict__ down)
{
  __shared__ bf16_t tmp0[64 * 128];
  __shared__ bf16_t tmp1[64 * 128];
  __shared__ bf16_t rbfA[64 * 32];     // K=32 zero-padded
  __shared__ float biasS[6 * 128];

  const int tid = threadIdx.x;
  const int lane = tid & 63, wv = tid >> 6;
  const int q = lane >> 4, l16 = lane & 15;
  const int mb = (wv >> 1) * 32, nb = (wv & 1) * 64;
  const int R = blockIdx.x * 64;

  for (int i = tid; i < 768; i += 256)
    biasS[i] = (i < 128) ? b_ji[i] : b_kj[i];
  if (tid < 64) {
    const float* rg = rbf + (size_t)(R + tid) * 6;
    bf16_t t[8] = {(bf16_t)rg[0], (bf16_t)rg[1], (bf16_t)rg[2],
                   (bf16_t)rg[3], (bf16_t)rg[4], (bf16_t)rg[5],
                   (bf16_t)0.f, (bf16_t)0.f};
    const uint4 z = {0, 0, 0, 0};
    bf16_t* dst = rbfA + tid * 32;
#pragma unroll
    for (int g = 0; g < 4; ++g) *(uint4*)(dst + g * 8) = z;
    *(uint4*)(dst + ((tid & 3) << 3)) = *(const uint4*)t;
  }

  // A-fragments of x (bf16) -> registers, reused for all 6 branches
  bf16x8 af0[4], af1[4];
  {
    const bf16_t* xr = xbf + (size_t)(R + mb + l16) * 128 + q * 8;
#pragma unroll
    for (int kt = 0; kt < 4; ++kt) {
      af0[kt] = *(const bf16x8*)(xr + kt * 32);
      af1[kt] = *(const bf16x8*)(xr + 16 * 128 + kt * 32);
    }
  }
  __syncthreads();

  // rbf A-fragments (K=32, one kt)
  bf16x8 ar0, ar1;
  {
    const int swr = (q ^ (l16 & 3)) << 3;
    ar0 = *(const bf16x8*)(rbfA + ((mb + l16) << 5) + swr);
    ar1 = *(const bf16x8*)(rbfA + ((mb + 16 + l16) << 5) + swr);
  }

  for (int br = 0; br < 6; ++br) {
    const bf16_t* WB = (br == 0) ? wjiT : wkjT + (size_t)(br - 1) * 16384;
    f32x4 acc[2][4] = {};
    gemm_rg<4, 4, 128>(af0, af1, WB, nb, l16, q, acc);

    if (br == 0) {
#pragma unroll
      for (int ti = 0; ti < 2; ++ti)
#pragma unroll
        for (int r = 0; r < 4; ++r) {
          const int row = mb + ti * 16 + q * 4 + r;
#pragma unroll
          for (int gl = 0; gl < 2; ++gl) {
            const int col0 = nb + gl * 32 + 2 * l16;
            const float2 b2 = *(const float2*)&biasS[col0];
            *(uint32_t*)&x_ji_out[(size_t)(R + row) * 128 + col0] =
                pack_bf16(silu_f(acc[ti][2 * gl][r] + b2.x),
                          silu_f(acc[ti][2 * gl + 1][r] + b2.y));
          }
        }
      continue;
    }

    // rbf_p = rbf @ Wc (K=6 padded to 32)
    f32x4 accr[2][4] = {};
    {
      const bf16_t* wb = wcb + (size_t)(br - 1) * 4096 + (nb + l16) * 32 + q * 8;
#pragma unroll
      for (int tj = 0; tj < 4; ++tj) {
        bf16x8 b = *(const bf16x8*)(wb + tj * 16 * 32);
        accr[0][tj] = __builtin_amdgcn_mfma_f32_16x16x32_bf16(ar0, b, accr[0][tj], 0, 0, 0);
        accr[1][tj] = __builtin_amdgcn_mfma_f32_16x16x32_bf16(ar1, b, accr[1][tj], 0, 0, 0);
      }
    }

    // tmp = silu(x@Wkj + b) * rbf_p -> swizzled LDS (ping-pong buffer)
    bf16_t* tp = (br & 1) ? tmp1 : tmp0;
#pragma unroll
    for (int ti = 0; ti < 2; ++ti)
#pragma unroll
      for (int r = 0; r < 4; ++r) {
        const int row = mb + ti * 16 + q * 4 + r;
#pragma unroll
        for (int gl = 0; gl < 2; ++gl) {
          const int col0 = nb + gl * 32 + 2 * l16;
          const float2 b2 = *(const float2*)&biasS[br * 128 + col0];
          const float v0 = silu_f(acc[ti][2 * gl][r] + b2.x) * accr[ti][2 * gl][r];
          const float v1 = silu_f(acc[ti][2 * gl + 1][r] + b2.y) * accr[ti][2 * gl + 1][r];
          *(uint32_t*)&tp[(row << 7) + ((((col0 >> 3) ^ (row & 15)) << 3) | (col0 & 7))] =
              pack_bf16(v0, v1);
        }
      }
    __syncthreads();

    const int nb2 = (wv & 1) * 32;
    f32x4 acc2[2][2] = {};
    gemm_bg<4, 2, 128>(tp, wdownT + (size_t)(br - 1) * 8192, mb, nb2, l16, q, acc2);
    // down layout: [E][5][64]
#pragma unroll
    for (int ti = 0; ti < 2; ++ti)
#pragma unroll
      for (int r = 0; r < 4; ++r) {
        const int row = mb + ti * 16 + q * 4 + r;
        const int col0 = nb2 + 2 * l16;
        *(uint32_t*)&down[((size_t)(R + row) * 5 + (br - 1)) * 64 + col0] =
            pack_bf16(silu_f(acc2[ti][0][r]), silu_f(acc2[ti][1][r]));
      }
  }
}

// =====================  K3: triplet — all-branch MFMA + select + pk-atomic scatter  =====================
__global__ __launch_bounds__(256, 3)
void triplet_kernel(const float* __restrict__ sbf, const int* __restrict__ idx_kj,
                    const int* __restrict__ idx_ji, const int* __restrict__ bt,
                    const float* __restrict__ alpha_p, const bf16_t* __restrict__ wsT,
                    const bf16_t* __restrict__ down, bf16_t* __restrict__ xkj)
{
  __shared__ bf16_t s_sbf[64 * 64];    // K=42 padded to 64, swizzle (k8^row&7)
  __shared__ bf16_t spC[64 * 344];     // [t][320 cols], pad for banks
  __shared__ int s_kj[64], s_ji[64], s_bs[64];

  const int tid = threadIdx.x;
  const int lane = tid & 63, wv = tid >> 6;
  const int q = lane >> 4, l16 = lane & 15;
  const int base = blockIdx.x * 64;

  if (tid < 64) {
    const int kj = idx_kj[base + tid];
    s_kj[tid] = kj;
    s_ji[tid] = idx_ji[base + tid];
    s_bs[tid] = bt[kj];   // 0..4 = slot of masked branch (branch = bt+1)
  }
#pragma unroll
  for (int it = 0; it < 2; ++it) {
    const int i = tid + it * 256;
    const int row = i >> 3, k8 = i & 7;
    const float* sg = sbf + (size_t)(base + row) * 42 + k8 * 8;
    bf16_t t[8];
#pragma unroll
    for (int jj = 0; jj < 8; ++jj)
      t[jj] = (k8 * 8 + jj < 42) ? (bf16_t)sg[jj] : (bf16_t)0.f;
    *(uint4*)(s_sbf + (row << 6) + ((k8 ^ (row & 7)) << 3)) = *(const uint4*)t;
  }
  __syncthreads();

  // GEMM: [64 x 48] @ [48 x 320] ; waves split M x 2, N x 2 (10 tiles each)
  const int mb = (wv & 1) * 32;
  const int tb0 = (wv >> 1) * 10;
  f32x4 acc[2][10] = {};
#pragma unroll
  for (int kt = 0; kt < 2; ++kt) {
    const int sw = (((kt << 2) + q) ^ (l16 & 7)) << 3;
    bf16x8 a0 = *(const bf16x8*)(s_sbf + ((mb + l16) << 6) + sw);
    bf16x8 a1 = *(const bf16x8*)(s_sbf + ((mb + 16 + l16) << 6) + sw);
    const bf16_t* bp = wsT + (tb0 * 16 + l16) * 64 + (kt << 5) + (q << 3);
#pragma unroll
    for (int tj = 0; tj < 10; ++tj) {
      bf16x8 b = *(const bf16x8*)(bp + tj * 1024);
      acc[0][tj] = __builtin_amdgcn_mfma_f32_16x16x32_bf16(a0, b, acc[0][tj], 0, 0, 0);
      acc[1][tj] = __builtin_amdgcn_mfma_f32_16x16x32_bf16(a1, b, acc[1][tj], 0, 0, 0);
    }
  }
#pragma unroll
  for (int ti = 0; ti < 2; ++ti)
#pragma unroll
    for (int r = 0; r < 4; ++r) {
      const int row = mb + ti * 16 + q * 4 + r;
#pragma unroll
      for (int tp = 0; tp < 5; ++tp) {
        const int t0 = tb0 + 2 * tp;
        const int col = (t0 >> 2) * 64 + (((t0 & 3) >> 1) << 5) + 2 * l16;
        *(uint32_t*)&spC[row * 344 + col] =
            pack_bf16(acc[ti][2 * tp][r], acc[ti][2 * tp + 1][r]);
      }
    }
  __syncthreads();

  // Phase 2: two triplets per wave-iteration; bf16x2 gathers + pk atomics.
  const float alpha = alpha_p[0];
  const float oma = 1.f - alpha;
  const int hf = lane >> 5;          // which triplet of the pair
  const int j0 = (lane & 31) * 2;    // 2 consecutive j per lane

  uint32_t G5[8], GB[8];
#pragma unroll
  for (int ii = 0; ii < 8; ++ii) {
    const int t = wv * 16 + ii * 2 + hf;
    const bf16_t* dr = down + (size_t)s_kj[t] * 320;
    G5[ii] = *(const uint32_t*)(dr + 256 + j0);
    GB[ii] = *(const uint32_t*)(dr + s_bs[t] * 64 + j0);
  }
#pragma unroll
  for (int ii = 0; ii < 8; ++ii) {
    const int t = wv * 16 + ii * 2 + hf;
    const int slot = s_bs[t];
    const int ji = s_ji[t];
    const float2 d5 = ubf2f(*(const uint32_t*)&spC[t * 344 + 256 + j0]);
    const float2 db = ubf2f(*(const uint32_t*)&spC[t * 344 + slot * 64 + j0]);
    const float2 g5 = ubf2f(G5[ii]);
    const float2 gb = ubf2f(GB[ii]);
    const float r0 = alpha * g5.x * d5.x + oma * gb.x * db.x;
    const float r1 = alpha * g5.y * d5.y + oma * gb.y * db.y;
    atomic_pk_add_bf16(&xkj[(size_t)ji * 64 + j0], pack_bf16(r0, r1));
  }
}

// =====================  K4: fused epilogue chain (512 threads, 8 waves)  =====================
__global__ __launch_bounds__(512, 4)
void epi_kernel(const float* __restrict__ x, const bf16_t* __restrict__ x_ji,
                const bf16_t* __restrict__ xkj,
                const bf16_t* __restrict__ wupT,
                const bf16_t* __restrict__ rb1T, const float* __restrict__ rb1_b,
                const bf16_t* __restrict__ rb2T, const float* __restrict__ rb2_b,
                const bf16_t* __restrict__ linT, const float* __restrict__ lin_b,
                const bf16_t* __restrict__ ra1T, const float* __restrict__ ra1_b,
                const bf16_t* __restrict__ ra2T, const float* __restrict__ ra2_b,
                float* __restrict__ out)
{
  __shared__ bf16_t bufA[64 * 128];
  __shared__ bf16_t bufB[64 * 128];
  __shared__ float biasAll[5 * 128];

  const int tid = threadIdx.x;
  const int lane = tid & 63, wv = tid >> 6;
  const int q = lane >> 4, l16 = lane & 15;
  const int mb = (wv >> 2) * 32, nb = (wv & 3) * 32;
  const int R = blockIdx.x * 64;

  { // stage xkj tile (bf16 [64][64]) -> swizzled LDS
    const int row = tid >> 3, k8 = tid & 7;
    *(uint4*)(bufA + (row << 7) + ((k8 ^ (row & 15)) << 3)) =
        ((const uint4*)(xkj + (size_t)R * 64))[tid];
  }
  if (tid < 128) {
    biasAll[tid]       = rb1_b[tid];
    biasAll[128 + tid] = rb2_b[tid];
    biasAll[256 + tid] = lin_b[tid];
    biasAll[384 + tid] = ra1_b[tid];
    biasAll[512 + tid] = ra2_b[tid];
  }
  __syncthreads();

  f32x4 hreg[2][2];
  { // h = x_ji + silu(xkj @ W_up)  -> bufB
    f32x4 acc[2][2] = {};
    gemm_bg<2, 2, 64>(bufA, wupT, mb, nb, l16, q, acc);
#pragma unroll
    for (int ti = 0; ti < 2; ++ti)
#pragma unroll
      for (int r = 0; r < 4; ++r) {
        const int row = mb + ti * 16 + q * 4 + r;
        const int col0 = nb + 2 * l16;
        union { uint32_t u; bf16x2 h; } xj;
        xj.u = *(const uint32_t*)&x_ji[(size_t)(R + row) * 128 + col0];
        const float h0 = (float)xj.h[0] + silu_f(acc[ti][0][r]);
        const float h1 = (float)xj.h[1] + silu_f(acc[ti][1][r]);
        hreg[ti][0][r] = h0;
        hreg[ti][1][r] = h1;
        *(uint32_t*)&bufB[(row << 7) + ((((col0 >> 3) ^ (row & 15)) << 3) | (col0 & 7))] =
            pack_bf16(h0, h1);
      }
  }

#define EPI_STAGE(ASRC, WPTR, BROW, BODY)                                        \
  __syncthreads();                                                               \
  {                                                                              \
    f32x4 acc[2][2] = {};                                                        \
    gemm_bg<4, 2, 128>(ASRC, WPTR, mb, nb, l16, q, acc);                         \
    _Pragma("unroll")                                                            \
    for (int ti = 0; ti < 2; ++ti)                                               \
      _Pragma("unroll")                                                          \
      for (int r = 0; r < 4; ++r) {                                              \
        const int row = mb + ti * 16 + q * 4 + r;                                \
        const int col0 = nb + 2 * l16;                                           \
        const float2 b2 = *(const float2*)&biasAll[BROW * 128 + col0];           \
        const float g0 = acc[ti][0][r] + b2.x;                                   \
        const float g1 = acc[ti][1][r] + b2.y;                                   \
        BODY                                                                     \
      }                                                                          \
  }

  // u = silu(h @ rb1 + b) -> bufA
  EPI_STAGE(bufB, rb1T, 0, {
    *(uint32_t*)&bufA[(row << 7) + ((((col0 >> 3) ^ (row & 15)) << 3) | (col0 & 7))] =
        pack_bf16(silu_f(g0), silu_f(g1));
  })

  // h += silu(u @ rb2 + b) -> bufB
  EPI_STAGE(bufA, rb2T, 1, {
    const float h0 = hreg[ti][0][r] + silu_f(g0);
    const float h1 = hreg[ti][1][r] + silu_f(g1);
    hreg[ti][0][r] = h0; hreg[ti][1][r] = h1;
    *(uint32_t*)&bufB[(row << 7) + ((((col0 >> 3) ^ (row & 15)) << 3) | (col0 & 7))] =
        pack_bf16(h0, h1);
  })

  // h = silu(h @ W_lin + b) + x -> bufA
  EPI_STAGE(bufB, linT, 2, {
    const float2 xv = *(const float2*)&x[(size_t)(R + row) * 128 + col0];
    const float h0 = silu_f(g0) + xv.x;
    const float h1 = silu_f(g1) + xv.y;
    hreg[ti][0][r] = h0; hreg[ti][1][r] = h1;
    *(uint32_t*)&bufA[(row << 7) + ((((col0 >> 3) ^ (row & 15)) << 3) | (col0 & 7))] =
        pack_bf16(h0, h1);
  })

  // u = silu(h @ ra1 + b) -> bufB
  EPI_STAGE(bufA, ra1T, 3, {
    *(uint32_t*)&bufB[(row << 7) + ((((col0 >> 3) ^ (row & 15)) << 3) | (col0 & 7))] =
        pack_bf16(silu_f(g0), silu_f(g1));
  })

  // out = h + silu(u @ ra2 + b)
  EPI_STAGE(bufB, ra2T, 4, {
    float2 o;
    o.x = hreg[ti][0][r] + silu_f(g0);
    o.y = hreg[ti][1][r] + silu_f(g1);
    *(float2*)&out[(size_t)(R + row) * 128 + col0] = o;
  })
#undef EPI_STAGE
}

extern "C" void kernel_launch(void* const* d_in, const int* in_sizes, int n_in,
                              void* d_out, int out_size, void* d_ws, size_t ws_size,
                              hipStream_t stream)
{
  (void)in_sizes; (void)n_in; (void)out_size; (void)ws_size;
  const float* x      = (const float*)d_in[0];
  const float* rbf    = (const float*)d_in[1];
  const float* sbf    = (const float*)d_in[2];
  const int*   idx_kj = (const int*)d_in[3];
  const int*   idx_ji = (const int*)d_in[4];
  const int*   bt     = (const int*)d_in[5];
  const float* alpha  = (const float*)d_in[7];
  const float* W_kj   = (const float*)d_in[8];
  const float* b_kj   = (const float*)d_in[9];
  const float* W_rbf1 = (const float*)d_in[10];
  const float* W_rbf2 = (const float*)d_in[11];
  const float* W_sbf1 = (const float*)d_in[12];
  const float* W_sbf2 = (const float*)d_in[13];
  const float* W_down = (const float*)d_in[14];
  const float* W_ji   = (const float*)d_in[15];
  const float* b_ji   = (const float*)d_in[16];
  const float* W_up   = (const float*)d_in[17];
  const float* rb1_w  = (const float*)d_in[18];
  const float* rb1_b  = (const float*)d_in[19];
  const float* rb2_w  = (const float*)d_in[20];
  const float* rb2_b  = (const float*)d_in[21];
  const float* W_lin  = (const float*)d_in[22];
  const float* b_lin  = (const float*)d_in[23];
  const float* ra1_w  = (const float*)d_in[24];
  const float* ra1_b  = (const float*)d_in[25];
  const float* ra2_w  = (const float*)d_in[26];
  const float* ra2_b  = (const float*)d_in[27];

  char* ws = (char*)d_ws;
  bf16_t* down   = (bf16_t*)(ws);                 // [E][5][64] bf16 = 41,943,040
  bf16_t* x_ji   = (bf16_t*)(ws + 41943040);      // E*128*2   = 16,777,216
  bf16_t* xkj    = (bf16_t*)(ws + 58720256);      // E*64*2    = 8,388,608
  bf16_t* xbf    = (bf16_t*)(ws + 67108864);      // E*128*2   = 16,777,216
  char* wbase    = ws + 83886080;
  bf16_t* wjiT   = (bf16_t*)(wbase + 0);
  bf16_t* wkjT   = (bf16_t*)(wbase + 32768);
  bf16_t* wdownT = (bf16_t*)(wbase + 196608);
  bf16_t* wupT   = (bf16_t*)(wbase + 278528);
  bf16_t* rb1T   = (bf16_t*)(wbase + 294912);
  bf16_t* rb2T   = (bf16_t*)(wbase + 327680);
  bf16_t* linT   = (bf16_t*)(wbase + 360448);
  bf16_t* ra1T   = (bf16_t*)(wbase + 393216);
  bf16_t* ra2T   = (bf16_t*)(wbase + 425984);
  bf16_t* wcb    = (bf16_t*)(wbase + 458752);     // 40,960
  bf16_t* wsT    = (bf16_t*)(wbase + 499712);     // 40,960

  hipMemsetAsync(xkj, 0, (size_t)E_N * 64 * 2, stream);
  prep_kernel<<<117, 256, 0, stream>>>(W_ji, W_kj, W_down, W_up, rb1_w, rb2_w,
                                       W_lin, ra1_w, ra2_w, W_rbf1, W_rbf2,
                                       W_sbf1, W_sbf2,
                                       wjiT, wkjT, wdownT, wupT, rb1T, rb2T,
                                       linT, ra1T, ra2T, wcb, wsT);
  xbf_kernel<<<E_N * 128 / 8 / 256, 256, 0, stream>>>(x, xbf);
  edge_kernel<<<E_N / 64, 256, 0, stream>>>(xbf, rbf, b_kj, b_ji, wjiT,
                                            wkjT, wdownT, wcb, x_ji, down);
  triplet_kernel<<<T_N / 64, 256, 0, stream>>>(sbf, idx_kj, idx_ji, bt, alpha,
                                               wsT, down, xkj);
  epi_kernel<<<E_N / 64, 512, 0, stream>>>(x, x_ji, xkj, wupT, rb1T, rb1_b,
                                           rb2T, rb2_b, linT, b_lin,
                                           ra1T, ra1_b, ra2T, ra2_b,
                                           (float*)d_out);
}

// Round 7
// 387.768 us; speedup vs baseline: 1.1576x; 1.1252x over previous
//
#include <hip/hip_runtime.h>
#include <hip/hip_bf16.h>
#include <stdint.h>

typedef __bf16 bf16_t;
typedef bf16_t bf16x8 __attribute__((ext_vector_type(8)));
typedef bf16_t bf16x2 __attribute__((ext_vector_type(2)));
typedef float f32x4 __attribute__((ext_vector_type(4)));

#define E_N 65536
#define T_N 262144

__device__ __forceinline__ float silu_f(float v) {
  return v / (1.0f + __expf(-v));
}

// B-row permutation: B row (tj*16+l16) holds real output column
// 32*(tj>>1) + 2*l16 + (tj&1) -> lane's acc pair = 2 consecutive real cols.
__device__ __forceinline__ int permrow(int n) {
  return (n & ~31) | ((n & 1) << 4) | ((n & 30) >> 1);
}

__device__ __forceinline__ uint32_t pack_bf16(float a, float b) {
  union { bf16x2 h; uint32_t u; } u;
  u.h[0] = (bf16_t)a; u.h[1] = (bf16_t)b;
  return u.u;
}

__device__ __forceinline__ float2 ubf2f(uint32_t v) {
  union { uint32_t u; bf16x2 h; } c; c.u = v;
  return make_float2((float)c.h[0], (float)c.h[1]);
}

// packed bf16x2 global atomic add (2 adds per atomic word)
__device__ __forceinline__ void atomic_pk_add_bf16(bf16_t* addr, uint32_t val) {
  asm volatile("global_atomic_pk_add_bf16 %0, %1, off" :: "v"(addr), "v"(val) : "memory");
}

__device__ __forceinline__ bf16x8 pack8(float4 a, float4 b) {
  union { bf16x8 v; uint32_t u[4]; } z;
  z.u[0] = pack_bf16(a.x, a.y); z.u[1] = pack_bf16(a.z, a.w);
  z.u[2] = pack_bf16(b.x, b.y); z.u[3] = pack_bf16(b.z, b.w);
  return z.v;
}

// ---- MFMA tile GEMM: A and B both from swizzled stride-128 LDS ----
// elem (row,k) at row*128 + (((k>>3) ^ (row&15))<<3) + (k&7)
template<int KI, int NTJ>
__device__ __forceinline__ void gemm_ls(const bf16_t* A, const bf16_t* B,
                                        int mb, int nb, int l16, int q,
                                        f32x4 (&acc)[2][NTJ]) {
#pragma unroll
  for (int kt = 0; kt < KI; ++kt) {
    const int sw = ((kt * 4 + q) ^ l16) << 3;
    bf16x8 a0 = *(const bf16x8*)(A + ((mb + l16) << 7) + sw);
    bf16x8 a1 = *(const bf16x8*)(A + ((mb + 16 + l16) << 7) + sw);
#pragma unroll
    for (int tj = 0; tj < NTJ; ++tj) {
      bf16x8 b = *(const bf16x8*)(B + ((nb + tj * 16 + l16) << 7) + sw);
      acc[0][tj] = __builtin_amdgcn_mfma_f32_16x16x32_bf16(a0, b, acc[0][tj], 0, 0, 0);
      acc[1][tj] = __builtin_amdgcn_mfma_f32_16x16x32_bf16(a1, b, acc[1][tj], 0, 0, 0);
    }
  }
}

// ---- MFMA tile GEMM: A from swizzled LDS, B direct from global (epi/triplet) ----
template<int KI, int NTJ, int BS>
__device__ __forceinline__ void gemm_bg(const bf16_t* A, const bf16_t* __restrict__ Bg,
                                        int mb, int nb, int l16, int q,
                                        f32x4 (&acc)[2][NTJ]) {
  bf16x8 bfr[KI][NTJ];
  const bf16_t* bp = Bg + (nb + l16) * BS + q * 8;
#pragma unroll
  for (int kt = 0; kt < KI; ++kt)
#pragma unroll
    for (int tj = 0; tj < NTJ; ++tj)
      bfr[kt][tj] = *(const bf16x8*)(bp + tj * 16 * BS + kt * 32);
#pragma unroll
  for (int kt = 0; kt < KI; ++kt) {
    const int sw = ((kt * 4 + q) ^ l16) << 3;
    bf16x8 a0 = *(const bf16x8*)(A + ((mb + l16) << 7) + sw);
    bf16x8 a1 = *(const bf16x8*)(A + ((mb + 16 + l16) << 7) + sw);
#pragma unroll
    for (int tj = 0; tj < NTJ; ++tj) {
      acc[0][tj] = __builtin_amdgcn_mfma_f32_16x16x32_bf16(a0, bfr[kt][tj], acc[0][tj], 0, 0, 0);
      acc[1][tj] = __builtin_amdgcn_mfma_f32_16x16x32_bf16(a1, bfr[kt][tj], acc[1][tj], 0, 0, 0);
    }
  }
}

// Stage bf16 [ROWS][128] global tile -> swizzled stride-128 LDS (uint4 units).
template<int ROWS>
__device__ __forceinline__ void stage_sw(bf16_t* dst, const bf16_t* __restrict__ src,
                                         int tid) {
  const uint4* g = (const uint4*)src;
#pragma unroll
  for (int i = tid; i < ROWS * 16; i += 256) {
    const int row = i >> 4, k8 = i & 15;
    *(uint4*)(dst + (row << 7) + ((k8 ^ (row & 15)) << 3)) = g[i];
  }
}

// Stage bf16 [64][64] tile -> swizzled bf16 LDS (stride 128).
__device__ __forceinline__ void stage_xkj(bf16_t* dst, const bf16_t* src, int tid) {
  const uint4* g = (const uint4*)src;
#pragma unroll
  for (int i = tid; i < 64 * 8; i += 256) {
    const int row = i >> 3, k8 = i & 7;
    *(uint4*)(dst + (row << 7) + ((k8 ^ (row & 15)) << 3)) = g[i];
  }
}

// =====================  K0: weight preprocessing  =====================
__global__ void prep_kernel(
    const float* __restrict__ W_ji, const float* __restrict__ W_kj,
    const float* __restrict__ W_down, const float* __restrict__ W_up,
    const float* __restrict__ rb1, const float* __restrict__ rb2,
    const float* __restrict__ W_lin, const float* __restrict__ ra1,
    const float* __restrict__ ra2, const float* __restrict__ W_rbf1,
    const float* __restrict__ W_rbf2, const float* __restrict__ W_sbf1,
    const float* __restrict__ W_sbf2,
    bf16_t* __restrict__ wjiT, bf16_t* __restrict__ wkjT,
    bf16_t* __restrict__ wdownT, bf16_t* __restrict__ wupT,
    bf16_t* __restrict__ rb1T, bf16_t* __restrict__ rb2T,
    bf16_t* __restrict__ linT, bf16_t* __restrict__ ra1T,
    bf16_t* __restrict__ ra2T, bf16_t* __restrict__ wcb,
    bf16_t* __restrict__ wsT)
{
  const int tid = threadIdx.x;
  const int bx = blockIdx.x;
  if (bx < 112) {
    const int c = bx * 256 + tid;
    const float* src; bf16_t* dst; int n, k8, N, K;
    if (c < 22528) {
      const int m = c >> 11, w = c & 2047;
      n = w >> 4; k8 = w & 15; N = 128; K = 128;
      if (m == 0)      { src = W_ji;  dst = wjiT; }
      else if (m <= 5) { src = W_kj + m * 16384; dst = wkjT + (m - 1) * 16384; }
      else if (m == 6) { src = rb1;   dst = rb1T; }
      else if (m == 7) { src = rb2;   dst = rb2T; }
      else if (m == 8) { src = W_lin; dst = linT; }
      else if (m == 9) { src = ra1;   dst = ra1T; }
      else             { src = ra2;   dst = ra2T; }
    } else if (c < 27648) {
      const int m = (c - 22528) >> 10, w = (c - 22528) & 1023;
      n = w >> 4; k8 = w & 15; N = 64; K = 128;
      src = W_down + (m + 1) * 8192; dst = wdownT + m * 8192;
    } else {
      const int w = c - 27648;
      n = w >> 3; k8 = w & 7; N = 128; K = 64;
      src = W_up; dst = wupT;
    }
    bf16_t t[8];
#pragma unroll
    for (int j = 0; j < 8; ++j) t[j] = (bf16_t)src[(k8 * 8 + j) * N + n];
    *(uint4*)(dst + permrow(n) * K + k8 * 8) = *(const uint4*)t;
  } else if (bx < 115) {
    const int o = (bx - 112) * 256 + tid;
    if (o < 640) {
      const int slot = o >> 7, n = o & 127;
      const int b = slot + 1;
      bf16_t t[32];
#pragma unroll
      for (int k = 0; k < 32; ++k) t[k] = (bf16_t)0.f;
#pragma unroll
      for (int r = 0; r < 6; ++r) {
        float s = 0.f;
#pragma unroll
        for (int c = 0; c < 8; ++c)
          s += W_rbf1[b * 48 + r * 8 + c] * W_rbf2[b * 1024 + c * 128 + n];
        t[r] = (bf16_t)s;
      }
      bf16_t* dst = wcb + slot * 4096 + permrow(n) * 32;
#pragma unroll
      for (int g = 0; g < 4; ++g) *(uint4*)(dst + g * 8) = *(const uint4*)(t + g * 8);
    }
  } else {
    const int o = (bx - 115) * 256 + tid;
    if (o < 320) {
      const int slot = o >> 6, j = o & 63;
      const int b = slot + 1;
      bf16_t t[64];
#pragma unroll
      for (int s = 0; s < 64; ++s) {
        float v = 0.f;
        if (s < 42) {
#pragma unroll
          for (int c = 0; c < 8; ++c)
            v += W_sbf1[b * 336 + s * 8 + c] * W_sbf2[b * 512 + c * 64 + j];
        }
        t[s] = (bf16_t)v;
      }
      bf16_t* dst = wsT + (slot * 64 + permrow(j)) * 64;
#pragma unroll
      for (int g = 0; g < 8; ++g) *(uint4*)(dst + g * 8) = *(const uint4*)(t + g * 8);
    }
  }
}

// =====================  K_xbf: x fp32 -> bf16 once  =====================
__global__ void xbf_kernel(const float* __restrict__ x, bf16_t* __restrict__ xbf) {
  const int i = blockIdx.x * 256 + threadIdx.x;
  float4 a = ((const float4*)x)[2 * i];
  float4 b = ((const float4*)x)[2 * i + 1];
  ((bf16x8*)xbf)[i] = pack8(a, b);
}

// =====================  K1: edge — branch-parallel, LDS-fed GEMMs  =====================
__global__ __launch_bounds__(256, 2)
void edge_kernel(const bf16_t* __restrict__ xbf, const float* __restrict__ rbf,
                 const float* __restrict__ b_kj, const float* __restrict__ b_ji,
                 const bf16_t* __restrict__ wjiT, const bf16_t* __restrict__ wkjT,
                 const bf16_t* __restrict__ wdownT, const bf16_t* __restrict__ wcb,
                 bf16_t* __restrict__ x_ji_out, bf16_t* __restrict__ down)
{
  __shared__ bf16_t xA[64 * 128];     // x tile; reused as Wdown B-tile for GEMM2
  __shared__ bf16_t Wb[128 * 128];
  __shared__ bf16_t tmpA[64 * 128];
  __shared__ bf16_t rbfA[64 * 32];    // K=32 zero-padded, swizzle (k8^(row&3))
  __shared__ float biasS[128];

  const int tid = threadIdx.x;
  const int lane = tid & 63, wv = tid >> 6;
  const int q = lane >> 4, l16 = lane & 15;
  const int mb = (wv >> 1) * 32, nb = (wv & 1) * 64;
  const int R = blockIdx.x * 64;
  const int br = blockIdx.y;   // 0 = x_ji, 1..5 = branch pipelines

  // rbf B-frags from global (tiny, L2-hot) issued early
  bf16x8 wcf[4];
  if (br != 0) {
    const bf16_t* wb = wcb + (size_t)(br - 1) * 4096 + (nb + l16) * 32 + q * 8;
#pragma unroll
    for (int tj = 0; tj < 4; ++tj) wcf[tj] = *(const bf16x8*)(wb + tj * 16 * 32);
  }

  stage_sw<64>(xA, xbf + (size_t)R * 128, tid);
  stage_sw<128>(Wb, (br == 0) ? wjiT : wkjT + (size_t)(br - 1) * 16384, tid);
  if (tid < 128) biasS[tid] = (br == 0) ? b_ji[tid] : b_kj[br * 128 + tid];
  if (br != 0 && tid < 64) {
    const float* rg = rbf + (size_t)(R + tid) * 6;
    bf16_t t[8] = {(bf16_t)rg[0], (bf16_t)rg[1], (bf16_t)rg[2],
                   (bf16_t)rg[3], (bf16_t)rg[4], (bf16_t)rg[5],
                   (bf16_t)0.f, (bf16_t)0.f};
    const uint4 z = {0, 0, 0, 0};
    bf16_t* dst = rbfA + tid * 32;
#pragma unroll
    for (int g = 0; g < 4; ++g) *(uint4*)(dst + g * 8) = z;
    *(uint4*)(dst + ((tid & 3) << 3)) = *(const uint4*)t;
  }
  __syncthreads();

  f32x4 acc[2][4] = {};
  gemm_ls<4, 4>(xA, Wb, mb, nb, l16, q, acc);

  if (br == 0) {
#pragma unroll
    for (int ti = 0; ti < 2; ++ti)
#pragma unroll
      for (int r = 0; r < 4; ++r) {
        const int row = mb + ti * 16 + q * 4 + r;
#pragma unroll
        for (int gl = 0; gl < 2; ++gl) {
          const int col0 = nb + gl * 32 + 2 * l16;
          const float2 b2 = *(const float2*)&biasS[col0];
          *(uint32_t*)&x_ji_out[(size_t)(R + row) * 128 + col0] =
              pack_bf16(silu_f(acc[ti][2 * gl][r] + b2.x),
                        silu_f(acc[ti][2 * gl + 1][r] + b2.y));
        }
      }
    return;
  }

  // rbf_p = rbf @ Wc (K=6 padded to 32)
  f32x4 accr[2][4] = {};
  {
    const int swr = (q ^ (l16 & 3)) << 3;
    bf16x8 a0 = *(const bf16x8*)(rbfA + ((mb + l16) << 5) + swr);
    bf16x8 a1 = *(const bf16x8*)(rbfA + ((mb + 16 + l16) << 5) + swr);
#pragma unroll
    for (int tj = 0; tj < 4; ++tj) {
      accr[0][tj] = __builtin_amdgcn_mfma_f32_16x16x32_bf16(a0, wcf[tj], accr[0][tj], 0, 0, 0);
      accr[1][tj] = __builtin_amdgcn_mfma_f32_16x16x32_bf16(a1, wcf[tj], accr[1][tj], 0, 0, 0);
    }
  }

  // tmp = silu(x@Wkj + b) * rbf_p  -> swizzled A-layout in tmpA
#pragma unroll
  for (int ti = 0; ti < 2; ++ti)
#pragma unroll
    for (int r = 0; r < 4; ++r) {
      const int row = mb + ti * 16 + q * 4 + r;
#pragma unroll
      for (int gl = 0; gl < 2; ++gl) {
        const int col0 = nb + gl * 32 + 2 * l16;
        const float2 b2 = *(const float2*)&biasS[col0];
        const float v0 = silu_f(acc[ti][2 * gl][r] + b2.x) * accr[ti][2 * gl][r];
        const float v1 = silu_f(acc[ti][2 * gl + 1][r] + b2.y) * accr[ti][2 * gl + 1][r];
        *(uint32_t*)&tmpA[(row << 7) + ((((col0 >> 3) ^ (row & 15)) << 3) | (col0 & 7))] =
            pack_bf16(v0, v1);
      }
    }
  __syncthreads();          // all GEMM1 reads of xA done, tmpA complete
  stage_sw<64>(xA, wdownT + (size_t)(br - 1) * 8192, tid);   // Wdown -> xA space
  __syncthreads();

  const int nb2 = (wv & 1) * 32;
  f32x4 acc2[2][2] = {};
  gemm_ls<4, 2>(tmpA, xA, mb, nb2, l16, q, acc2);
  // down layout: [E][5][64]
#pragma unroll
  for (int ti = 0; ti < 2; ++ti)
#pragma unroll
    for (int r = 0; r < 4; ++r) {
      const int row = mb + ti * 16 + q * 4 + r;
      const int col0 = nb2 + 2 * l16;
      *(uint32_t*)&down[((size_t)(R + row) * 5 + (br - 1)) * 64 + col0] =
          pack_bf16(silu_f(acc2[ti][0][r]), silu_f(acc2[ti][1][r]));
    }
}

// =====================  K3: triplet — all-branch MFMA + select + pk-atomic scatter  =====================
__global__ __launch_bounds__(256, 3)
void triplet_kernel(const float* __restrict__ sbf, const int* __restrict__ idx_kj,
                    const int* __restrict__ idx_ji, const int* __restrict__ bt,
                    const float* __restrict__ alpha_p, const bf16_t* __restrict__ wsT,
                    const bf16_t* __restrict__ down, bf16_t* __restrict__ xkj)
{
  __shared__ bf16_t s_sbf[64 * 64];    // K=42 padded to 64, swizzle (k8^row&7)
  __shared__ bf16_t spC[64 * 344];     // [t][320 cols], pad for banks
  __shared__ int s_kj[64], s_ji[64], s_bs[64];

  const int tid = threadIdx.x;
  const int lane = tid & 63, wv = tid >> 6;
  const int q = lane >> 4, l16 = lane & 15;
  const int base = blockIdx.x * 64;

  if (tid < 64) {
    const int kj = idx_kj[base + tid];
    s_kj[tid] = kj;
    s_ji[tid] = idx_ji[base + tid];
    s_bs[tid] = bt[kj];   // 0..4 = slot of masked branch (branch = bt+1)
  }
#pragma unroll
  for (int it = 0; it < 2; ++it) {
    const int i = tid + it * 256;
    const int row = i >> 3, k8 = i & 7;
    const float* sg = sbf + (size_t)(base + row) * 42 + k8 * 8;
    bf16_t t[8];
#pragma unroll
    for (int jj = 0; jj < 8; ++jj)
      t[jj] = (k8 * 8 + jj < 42) ? (bf16_t)sg[jj] : (bf16_t)0.f;
    *(uint4*)(s_sbf + (row << 6) + ((k8 ^ (row & 7)) << 3)) = *(const uint4*)t;
  }
  __syncthreads();

  // GEMM: [64 x 48] @ [48 x 320] ; waves split M x 2, N x 2 (10 tiles each)
  const int mb = (wv & 1) * 32;
  const int tb0 = (wv >> 1) * 10;
  f32x4 acc[2][10] = {};
#pragma unroll
  for (int kt = 0; kt < 2; ++kt) {
    const int sw = (((kt << 2) + q) ^ (l16 & 7)) << 3;
    bf16x8 a0 = *(const bf16x8*)(s_sbf + ((mb + l16) << 6) + sw);
    bf16x8 a1 = *(const bf16x8*)(s_sbf + ((mb + 16 + l16) << 6) + sw);
    const bf16_t* bp = wsT + (tb0 * 16 + l16) * 64 + (kt << 5) + (q << 3);
#pragma unroll
    for (int tj = 0; tj < 10; ++tj) {
      bf16x8 b = *(const bf16x8*)(bp + tj * 1024);
      acc[0][tj] = __builtin_amdgcn_mfma_f32_16x16x32_bf16(a0, b, acc[0][tj], 0, 0, 0);
      acc[1][tj] = __builtin_amdgcn_mfma_f32_16x16x32_bf16(a1, b, acc[1][tj], 0, 0, 0);
    }
  }
#pragma unroll
  for (int ti = 0; ti < 2; ++ti)
#pragma unroll
    for (int r = 0; r < 4; ++r) {
      const int row = mb + ti * 16 + q * 4 + r;
#pragma unroll
      for (int tp = 0; tp < 5; ++tp) {
        const int t0 = tb0 + 2 * tp;
        const int col = (t0 >> 2) * 64 + (((t0 & 3) >> 1) << 5) + 2 * l16;
        *(uint32_t*)&spC[row * 344 + col] =
            pack_bf16(acc[ti][2 * tp][r], acc[ti][2 * tp + 1][r]);
      }
    }
  __syncthreads();

  // Phase 2: two triplets per wave-iteration; bf16x2 gathers + pk atomics.
  const float alpha = alpha_p[0];
  const float oma = 1.f - alpha;
  const int hf = lane >> 5;          // which triplet of the pair
  const int j0 = (lane & 31) * 2;    // 2 consecutive j per lane

  uint32_t G5[8], GB[8];
#pragma unroll
  for (int ii = 0; ii < 8; ++ii) {
    const int t = wv * 16 + ii * 2 + hf;
    const bf16_t* dr = down + (size_t)s_kj[t] * 320;
    G5[ii] = *(const uint32_t*)(dr + 256 + j0);
    GB[ii] = *(const uint32_t*)(dr + s_bs[t] * 64 + j0);
  }
#pragma unroll
  for (int ii = 0; ii < 8; ++ii) {
    const int t = wv * 16 + ii * 2 + hf;
    const int slot = s_bs[t];
    const int ji = s_ji[t];
    const float2 d5 = ubf2f(*(const uint32_t*)&spC[t * 344 + 256 + j0]);
    const float2 db = ubf2f(*(const uint32_t*)&spC[t * 344 + slot * 64 + j0]);
    const float2 g5 = ubf2f(G5[ii]);
    const float2 gb = ubf2f(GB[ii]);
    const float r0 = alpha * g5.x * d5.x + oma * gb.x * db.x;
    const float r1 = alpha * g5.y * d5.y + oma * gb.y * db.y;
    atomic_pk_add_bf16(&xkj[(size_t)ji * 64 + j0], pack_bf16(r0, r1));
  }
}

// =====================  K4: fused epilogue chain (256 threads — Round-4 proven)  =====================
__global__ __launch_bounds__(256, 3)
void epi_kernel(const float* __restrict__ x, const bf16_t* __restrict__ x_ji,
                const bf16_t* __restrict__ xkj,
                const bf16_t* __restrict__ wupT,
                const bf16_t* __restrict__ rb1T, const float* __restrict__ rb1_b,
                const bf16_t* __restrict__ rb2T, const float* __restrict__ rb2_b,
                const bf16_t* __restrict__ linT, const float* __restrict__ lin_b,
                const bf16_t* __restrict__ ra1T, const float* __restrict__ ra1_b,
                const bf16_t* __restrict__ ra2T, const float* __restrict__ ra2_b,
                float* __restrict__ out)
{
  __shared__ bf16_t bufA[64 * 128];
  __shared__ bf16_t bufB[64 * 128];
  __shared__ float biasAll[5 * 128];

  const int tid = threadIdx.x;
  const int lane = tid & 63, wv = tid >> 6;
  const int q = lane >> 4, l16 = lane & 15;
  const int mb = (wv >> 1) * 32, nb = (wv & 1) * 64;
  const int R = blockIdx.x * 64;

  stage_xkj(bufA, xkj + (size_t)R * 64, tid);
  if (tid < 128) {
    biasAll[tid]       = rb1_b[tid];
    biasAll[128 + tid] = rb2_b[tid];
    biasAll[256 + tid] = lin_b[tid];
    biasAll[384 + tid] = ra1_b[tid];
    biasAll[512 + tid] = ra2_b[tid];
  }
  __syncthreads();

  f32x4 hreg[2][4];
  { // h = x_ji + silu(xkj @ W_up)  -> bufB
    f32x4 acc[2][4] = {};
    gemm_bg<2, 4, 64>(bufA, wupT, mb, nb, l16, q, acc);
#pragma unroll
    for (int ti = 0; ti < 2; ++ti)
#pragma unroll
      for (int r = 0; r < 4; ++r) {
        const int row = mb + ti * 16 + q * 4 + r;
#pragma unroll
        for (int gl = 0; gl < 2; ++gl) {
          const int col0 = nb + gl * 32 + 2 * l16;
          union { uint32_t u; bf16x2 h; } xj;
          xj.u = *(const uint32_t*)&x_ji[(size_t)(R + row) * 128 + col0];
          const float h0 = (float)xj.h[0] + silu_f(acc[ti][2 * gl][r]);
          const float h1 = (float)xj.h[1] + silu_f(acc[ti][2 * gl + 1][r]);
          hreg[ti][2 * gl][r] = h0;
          hreg[ti][2 * gl + 1][r] = h1;
          *(uint32_t*)&bufB[(row << 7) + ((((col0 >> 3) ^ (row & 15)) << 3) | (col0 & 7))] =
              pack_bf16(h0, h1);
        }
      }
  }

#define EPI_STAGE(ASRC, WPTR, BROW, BODY)                                        \
  __syncthreads();                                                               \
  {                                                                              \
    f32x4 acc[2][4] = {};                                                        \
    gemm_bg<4, 4, 128>(ASRC, WPTR, mb, nb, l16, q, acc);                         \
    _Pragma("unroll")                                                            \
    for (int ti = 0; ti < 2; ++ti)                                               \
      _Pragma("unroll")                                                          \
      for (int r = 0; r < 4; ++r) {                                              \
        const int row = mb + ti * 16 + q * 4 + r;                                \
        _Pragma("unroll")                                                        \
        for (int gl = 0; gl < 2; ++gl) {                                         \
          const int col0 = nb + gl * 32 + 2 * l16;                               \
          const float2 b2 = *(const float2*)&biasAll[BROW * 128 + col0];         \
          const float g0 = acc[ti][2 * gl][r] + b2.x;                            \
          const float g1 = acc[ti][2 * gl + 1][r] + b2.y;                        \
          BODY                                                                   \
        }                                                                        \
      }                                                                          \
  }

  // u = silu(h @ rb1 + b) -> bufA
  EPI_STAGE(bufB, rb1T, 0, {
    *(uint32_t*)&bufA[(row << 7) + ((((col0 >> 3) ^ (row & 15)) << 3) | (col0 & 7))] =
        pack_bf16(silu_f(g0), silu_f(g1));
  })

  // h += silu(u @ rb2 + b) -> bufB
  EPI_STAGE(bufA, rb2T, 1, {
    const float h0 = hreg[ti][2 * gl][r] + silu_f(g0);
    const float h1 = hreg[ti][2 * gl + 1][r] + silu_f(g1);
    hreg[ti][2 * gl][r] = h0; hreg[ti][2 * gl + 1][r] = h1;
    *(uint32_t*)&bufB[(row << 7) + ((((col0 >> 3) ^ (row & 15)) << 3) | (col0 & 7))] =
        pack_bf16(h0, h1);
  })

  // h = silu(h @ W_lin + b) + x -> bufA
  EPI_STAGE(bufB, linT, 2, {
    const float2 xv = *(const float2*)&x[(size_t)(R + row) * 128 + col0];
    const float h0 = silu_f(g0) + xv.x;
    const float h1 = silu_f(g1) + xv.y;
    hreg[ti][2 * gl][r] = h0; hreg[ti][2 * gl + 1][r] = h1;
    *(uint32_t*)&bufA[(row << 7) + ((((col0 >> 3) ^ (row & 15)) << 3) | (col0 & 7))] =
        pack_bf16(h0, h1);
  })

  // u = silu(h @ ra1 + b) -> bufB
  EPI_STAGE(bufA, ra1T, 3, {
    *(uint32_t*)&bufB[(row << 7) + ((((col0 >> 3) ^ (row & 15)) << 3) | (col0 & 7))] =
        pack_bf16(silu_f(g0), silu_f(g1));
  })

  // out = h + silu(u @ ra2 + b)
  EPI_STAGE(bufB, ra2T, 4, {
    float2 o;
    o.x = hreg[ti][2 * gl][r] + silu_f(g0);
    o.y = hreg[ti][2 * gl + 1][r] + silu_f(g1);
    *(float2*)&out[(size_t)(R + row) * 128 + col0] = o;
  })
#undef EPI_STAGE
}

extern "C" void kernel_launch(void* const* d_in, const int* in_sizes, int n_in,
                              void* d_out, int out_size, void* d_ws, size_t ws_size,
                              hipStream_t stream)
{
  (void)in_sizes; (void)n_in; (void)out_size; (void)ws_size;
  const float* x      = (const float*)d_in[0];
  const float* rbf    = (const float*)d_in[1];
  const float* sbf    = (const float*)d_in[2];
  const int*   idx_kj = (const int*)d_in[3];
  const int*   idx_ji = (const int*)d_in[4];
  const int*   bt     = (const int*)d_in[5];
  const float* alpha  = (const float*)d_in[7];
  const float* W_kj   = (const float*)d_in[8];
  const float* b_kj   = (const float*)d_in[9];
  const float* W_rbf1 = (const float*)d_in[10];
  const float* W_rbf2 = (const float*)d_in[11];
  const float* W_sbf1 = (const float*)d_in[12];
  const float* W_sbf2 = (const float*)d_in[13];
  const float* W_down = (const float*)d_in[14];
  const float* W_ji   = (const float*)d_in[15];
  const float* b_ji   = (const float*)d_in[16];
  const float* W_up   = (const float*)d_in[17];
  const float* rb1_w  = (const float*)d_in[18];
  const float* rb1_b  = (const float*)d_in[19];
  const float* rb2_w  = (const float*)d_in[20];
  const float* rb2_b  = (const float*)d_in[21];
  const float* W_lin  = (const float*)d_in[22];
  const float* b_lin  = (const float*)d_in[23];
  const float* ra1_w  = (const float*)d_in[24];
  const float* ra1_b  = (const float*)d_in[25];
  const float* ra2_w  = (const float*)d_in[26];
  const float* ra2_b  = (const float*)d_in[27];

  char* ws = (char*)d_ws;
  bf16_t* down   = (bf16_t*)(ws);                 // [E][5][64] bf16 = 41,943,040
  bf16_t* x_ji   = (bf16_t*)(ws + 41943040);      // E*128*2   = 16,777,216
  bf16_t* xkj    = (bf16_t*)(ws + 58720256);      // E*64*2    = 8,388,608
  bf16_t* xbf    = (bf16_t*)(ws + 67108864);      // E*128*2   = 16,777,216
  char* wbase    = ws + 83886080;
  bf16_t* wjiT   = (bf16_t*)(wbase + 0);
  bf16_t* wkjT   = (bf16_t*)(wbase + 32768);
  bf16_t* wdownT = (bf16_t*)(wbase + 196608);
  bf16_t* wupT   = (bf16_t*)(wbase + 278528);
  bf16_t* rb1T   = (bf16_t*)(wbase + 294912);
  bf16_t* rb2T   = (bf16_t*)(wbase + 327680);
  bf16_t* linT   = (bf16_t*)(wbase + 360448);
  bf16_t* ra1T   = (bf16_t*)(wbase + 393216);
  bf16_t* ra2T   = (bf16_t*)(wbase + 425984);
  bf16_t* wcb    = (bf16_t*)(wbase + 458752);     // 40,960
  bf16_t* wsT    = (bf16_t*)(wbase + 499712);     // 40,960

  hipMemsetAsync(xkj, 0, (size_t)E_N * 64 * 2, stream);
  prep_kernel<<<117, 256, 0, stream>>>(W_ji, W_kj, W_down, W_up, rb1_w, rb2_w,
                                       W_lin, ra1_w, ra2_w, W_rbf1, W_rbf2,
                                       W_sbf1, W_sbf2,
                                       wjiT, wkjT, wdownT, wupT, rb1T, rb2T,
                                       linT, ra1T, ra2T, wcb, wsT);
  xbf_kernel<<<E_N * 128 / 8 / 256, 256, 0, stream>>>(x, xbf);
  edge_kernel<<<dim3(E_N / 64, 6), 256, 0, stream>>>(xbf, rbf, b_kj, b_ji, wjiT,
                                                     wkjT, wdownT, wcb, x_ji, down);
  triplet_kernel<<<T_N / 64, 256, 0, stream>>>(sbf, idx_kj, idx_ji, bt, alpha,
                                               wsT, down, xkj);
  epi_kernel<<<E_N / 64, 256, 0, stream>>>(x, x_ji, xkj, wupT, rb1T, rb1_b,
                                           rb2T, rb2_b, linT, b_lin,
                                           ra1T, ra1_b, ra2T, ra2_b,
                                           (float*)d_out);
}